// Round 1
// baseline (1291.914 us; speedup 1.0000x reference)
//
#include <hip/hip_runtime.h>

// ---------------------------------------------------------------------------
// Segment-mean (MeanAggregator): out[m, :] = mean over atoms of molecule m.
// segment_ids are sorted; every molecule has >= 1 atom.
// Memory-bound: ~1.03 GB read + ~52 MB write -> roofline ~172 us @ 6.3 TB/s.
// ---------------------------------------------------------------------------

__device__ __forceinline__ float4 f4add(float4 a, float4 b) {
    return make_float4(a.x + b.x, a.y + b.y, a.z + b.z, a.w + b.w);
}

// Kernel A: find segment start offsets from sorted segment_ids.
// starts[m] = first atom index of molecule m; starts[n_mols] = n_atoms.
__global__ void seg_starts_kernel(const int* __restrict__ seg,
                                  int* __restrict__ starts,
                                  int n_atoms, int n_mols) {
    int i = blockIdx.x * blockDim.x + threadIdx.x;
    if (i >= n_atoms) return;
    int s = seg[i];
    if (i == 0) {
        starts[s] = 0;
        starts[n_mols] = n_atoms;
    } else if (seg[i - 1] != s) {
        starts[s] = i;
    }
}

// Kernel B: one thread per output float4. Lane l of a group of 32 handles
// column float4 (l & 31) -> each wave load = two contiguous 512 B rows,
// fully coalesced. 4x unrolled row loop keeps 4 loads in flight.
__global__ void seg_mean_kernel(const float4* __restrict__ a4,
                                const int* __restrict__ starts,
                                float4* __restrict__ out4,
                                int cols4, long long n_out4) {
    long long idx = (long long)blockIdx.x * blockDim.x + threadIdx.x;
    if (idx >= n_out4) return;
    int mol = (int)(idx / cols4);
    int col = (int)(idx - (long long)mol * cols4);

    int start = starts[mol];
    int end   = starts[mol + 1];
    int cnt   = end - start;

    const float4* p = a4 + (long long)start * cols4 + col;
    float4 acc = make_float4(0.f, 0.f, 0.f, 0.f);

    int r = 0;
    for (; r + 4 <= cnt; r += 4) {
        float4 a = p[(long long)(r + 0) * cols4];
        float4 b = p[(long long)(r + 1) * cols4];
        float4 c = p[(long long)(r + 2) * cols4];
        float4 d = p[(long long)(r + 3) * cols4];
        acc = f4add(acc, f4add(f4add(a, b), f4add(c, d)));
    }
    for (; r < cnt; ++r) {
        acc = f4add(acc, p[(long long)r * cols4]);
    }

    float inv = 1.0f; // cnt >= 1 guaranteed
    float fc = (float)cnt;
    acc.x = acc.x / fc;
    acc.y = acc.y / fc;
    acc.z = acc.z / fc;
    acc.w = acc.w / fc;
    (void)inv;

    out4[idx] = acc;
}

// Fallback (ws too small): per-thread binary search for segment boundaries.
// segment_ids (8 MB) is L2/L3-resident; all 32 lanes of a group probe the
// same addresses -> broadcast, cheap.
__device__ __forceinline__ int lower_bound_dev(const int* __restrict__ seg,
                                               int n, int val) {
    int lo = 0, hi = n;
    while (lo < hi) {
        int mid = (lo + hi) >> 1;
        if (seg[mid] < val) lo = mid + 1; else hi = mid;
    }
    return lo;
}

__global__ void seg_mean_bsearch_kernel(const float4* __restrict__ a4,
                                        const int* __restrict__ seg,
                                        float4* __restrict__ out4,
                                        int cols4, int n_atoms,
                                        long long n_out4) {
    long long idx = (long long)blockIdx.x * blockDim.x + threadIdx.x;
    if (idx >= n_out4) return;
    int mol = (int)(idx / cols4);
    int col = (int)(idx - (long long)mol * cols4);

    int start = lower_bound_dev(seg, n_atoms, mol);
    int end   = lower_bound_dev(seg, n_atoms, mol + 1);
    int cnt   = end - start;

    const float4* p = a4 + (long long)start * cols4 + col;
    float4 acc = make_float4(0.f, 0.f, 0.f, 0.f);

    int r = 0;
    for (; r + 4 <= cnt; r += 4) {
        float4 a = p[(long long)(r + 0) * cols4];
        float4 b = p[(long long)(r + 1) * cols4];
        float4 c = p[(long long)(r + 2) * cols4];
        float4 d = p[(long long)(r + 3) * cols4];
        acc = f4add(acc, f4add(f4add(a, b), f4add(c, d)));
    }
    for (; r < cnt; ++r) {
        acc = f4add(acc, p[(long long)r * cols4]);
    }

    float fc = (float)cnt;
    acc.x = acc.x / fc;
    acc.y = acc.y / fc;
    acc.z = acc.z / fc;
    acc.w = acc.w / fc;

    out4[idx] = acc;
}

extern "C" void kernel_launch(void* const* d_in, const int* in_sizes, int n_in,
                              void* d_out, int out_size, void* d_ws, size_t ws_size,
                              hipStream_t stream) {
    const float* atom_hiddens = (const float*)d_in[0];
    const int*   segment_ids  = (const int*)d_in[1];
    // d_in[2] is n_mols on device; derive everything host-side from sizes
    // (graph-capture safe, no readback).
    int n_atoms = in_sizes[1];
    int hidden  = in_sizes[0] / n_atoms;   // 128
    int n_mols  = out_size / hidden;       // 100000
    int cols4   = hidden / 4;              // 32

    long long n_out4 = (long long)n_mols * cols4;
    int blk = 256;
    int grid_mean = (int)((n_out4 + blk - 1) / blk);

    size_t starts_bytes = (size_t)(n_mols + 1) * sizeof(int);
    if (ws_size >= starts_bytes) {
        int* starts = (int*)d_ws;
        int grid_starts = (n_atoms + blk - 1) / blk;
        seg_starts_kernel<<<grid_starts, blk, 0, stream>>>(segment_ids, starts,
                                                           n_atoms, n_mols);
        seg_mean_kernel<<<grid_mean, blk, 0, stream>>>(
            (const float4*)atom_hiddens, starts, (float4*)d_out, cols4, n_out4);
    } else {
        seg_mean_bsearch_kernel<<<grid_mean, blk, 0, stream>>>(
            (const float4*)atom_hiddens, segment_ids, (float4*)d_out,
            cols4, n_atoms, n_out4);
    }
}